// Round 1
// baseline (3688.472 us; speedup 1.0000x reference)
//
#include <hip/hip_runtime.h>
#include <hip/hip_bf16.h>

// VQ-VAE EMA vector quantizer, MI355X.
// Shapes: z_e (16,256,64,64) f32, codebook (2048,256) f32, ema_count (2048) f32,
//         ema_weight (2048,256) f32.
// Outputs (flat f32 concat): z_q_st (16,256,64,64) | idx (16,64,64) as float |
//         loss (1) | new_codebook (2048,256) | new_ema_count (2048) | new_ema_weight (2048,256)

#define KC 2048
#define DD 256
#define NB 16
#define HWS 4096
#define NPTS 65536          // NB*HWS
#define DECAYF 0.99f
#define ONEMD 0.01f
#define EPSF 1e-5f

// ---- workspace layout (bytes) ----
#define WS_IDX    0                         // int32 [65536]
#define WS_CNORM  (WS_IDX + NPTS*4)         // f32 [2048]
#define WS_COUNTS (WS_CNORM + KC*4)         // f32 [2048]   (zeroed per call)
#define WS_DW     (WS_COUNTS + KC*4)        // f32 [2048*256] (zeroed per call)
#define WS_LOSSP  (WS_DW + KC*DD*4)         // f32 [65536] block partials
#define WS_NEED   (WS_LOSSP + 65536*4)      // ~2.64 MB total

// ---- output offsets (floats) ----
#define OUT_ZQ   0
#define OUT_IDX  16777216
#define OUT_LOSS (OUT_IDX + NPTS)
#define OUT_CB   (OUT_LOSS + 1)
#define OUT_CNT  (OUT_CB + KC*DD)
#define OUT_W    (OUT_CNT + KC)

// ---------------------------------------------------------------------------
__global__ __launch_bounds__(256) void cnorm_kernel(const float* __restrict__ cb,
                                                    float* __restrict__ cnorm) {
    int k = blockIdx.x * 256 + threadIdx.x;
    if (k < KC) {
        const float4* row = reinterpret_cast<const float4*>(cb + (size_t)k * DD);
        float s = 0.f;
        #pragma unroll 8
        for (int i = 0; i < DD / 4; ++i) {
            float4 v = row[i];
            s += v.x * v.x + v.y * v.y + v.z * v.z + v.w * v.w;
        }
        cnorm[k] = s;
    }
}

// ---------------------------------------------------------------------------
// Distance + argmin. Block = 256 threads (16x16 micro-grid), tile = 64 points
// x 64 codes, K-loop over 32 code tiles, D-chunks of 64 staged in LDS.
// dist' = ||c||^2 - 2*x.c  (the ||x||^2 term is constant per point -> dropped
// for argmin purposes).
#define PT 64
#define KT 64
#define DC 64

__global__ __launch_bounds__(256) void argmin_kernel(const float* __restrict__ z_e,
                                                     const float* __restrict__ cb,
                                                     const float* __restrict__ cnorm,
                                                     int* __restrict__ idx_out) {
    __shared__ float As[DC][PT + 4];   // [d][point]
    __shared__ float Bs[DC][KT + 4];   // [d][code]
    __shared__ float rv[PT][16];
    __shared__ int   ri[PT][16];

    const int tid = threadIdx.x;
    const int tx = tid & 15, ty = tid >> 4;
    const int n0 = blockIdx.x * PT;
    const int b = n0 >> 12;
    const int hw0 = n0 & 4095;
    const float* zb = z_e + (size_t)b * DD * HWS + hw0;

    float bestv[4];
    int   besti[4];
    #pragma unroll
    for (int j = 0; j < 4; ++j) { bestv[j] = 3.4e38f; besti[j] = 0; }

    for (int kt = 0; kt < KC; kt += KT) {
        float acc[4][4] = {};
        for (int dc = 0; dc < DD; dc += DC) {
            // stage A: 64 d x 64 points
            #pragma unroll
            for (int i = 0; i < 16; ++i) {
                int li = tid + i * 256;
                int d = li >> 6, p = li & 63;
                As[d][p] = zb[(size_t)(dc + d) * HWS + p];
            }
            // stage B: 64 codes x 64 d, transposed into [d][k]
            #pragma unroll
            for (int i = 0; i < 16; ++i) {
                int li = tid + i * 256;
                int k = li >> 6, d = li & 63;
                Bs[d][k] = cb[(size_t)(kt + k) * DD + dc + d];
            }
            __syncthreads();
            #pragma unroll
            for (int d = 0; d < DC; ++d) {
                const float4 a4 = *reinterpret_cast<const float4*>(&As[d][ty * 4]);
                const float4 b4 = *reinterpret_cast<const float4*>(&Bs[d][tx * 4]);
                const float a[4] = {a4.x, a4.y, a4.z, a4.w};
                const float bb[4] = {b4.x, b4.y, b4.z, b4.w};
                #pragma unroll
                for (int j = 0; j < 4; ++j)
                    #pragma unroll
                    for (int i = 0; i < 4; ++i)
                        acc[j][i] = fmaf(a[j], bb[i], acc[j][i]);
            }
            __syncthreads();
        }
        // distances & running argmin (k increasing -> strict < keeps first min)
        #pragma unroll
        for (int i = 0; i < 4; ++i) {
            int k = kt + tx * 4 + i;
            float c = cnorm[k];
            #pragma unroll
            for (int j = 0; j < 4; ++j) {
                float dist = c - 2.0f * acc[j][i];
                if (dist < bestv[j]) { bestv[j] = dist; besti[j] = k; }
            }
        }
    }

    #pragma unroll
    for (int j = 0; j < 4; ++j) {
        rv[ty * 4 + j][tx] = bestv[j];
        ri[ty * 4 + j][tx] = besti[j];
    }
    __syncthreads();
    if (tid < PT) {
        float bv = rv[tid][0];
        int bi = ri[tid][0];
        #pragma unroll
        for (int t = 1; t < 16; ++t) {
            float v = rv[tid][t];
            int i2 = ri[tid][t];
            if (v < bv || (v == bv && i2 < bi)) { bv = v; bi = i2; }
        }
        idx_out[n0 + tid] = bi;
    }
}

// ---------------------------------------------------------------------------
// z_q gather + straight-through output + commitment-loss block partials.
__global__ __launch_bounds__(256) void zq_loss_kernel(const float* __restrict__ z_e,
                                                      const float* __restrict__ cb,
                                                      const int* __restrict__ idx,
                                                      float* __restrict__ out_zq,
                                                      float* __restrict__ lossp) {
    const int tid = threadIdx.x;
    const size_t o = (size_t)blockIdx.x * 256 + tid;
    const int hw = (int)(o & 4095);
    const int d = (int)((o >> 12) & 255);
    const int b = (int)(o >> 20);
    const int n = b * HWS + hw;

    const float ze = z_e[o];
    const float q = cb[(size_t)idx[n] * DD + d];
    out_zq[o] = ze + (q - ze);          // straight-through fwd value (match ref rounding)
    float diff = ze - q;
    float v = diff * diff;

    #pragma unroll
    for (int off = 32; off > 0; off >>= 1) v += __shfl_down(v, off, 64);
    __shared__ float wsum[4];
    if ((tid & 63) == 0) wsum[tid >> 6] = v;
    __syncthreads();
    if (tid == 0) lossp[blockIdx.x] = wsum[0] + wsum[1] + wsum[2] + wsum[3];
}

__global__ __launch_bounds__(256) void loss_finalize_kernel(const float* __restrict__ lossp,
                                                            float* __restrict__ out_loss) {
    __shared__ double sd[256];
    const int tid = threadIdx.x;
    double s = 0.0;
    for (int i = tid; i < 65536; i += 256) s += (double)lossp[i];
    sd[tid] = s;
    __syncthreads();
    for (int off = 128; off > 0; off >>= 1) {
        if (tid < off) sd[tid] += sd[tid + off];
        __syncthreads();
    }
    if (tid == 0) out_loss[0] = (float)(sd[0] / 16777216.0);
}

// ---------------------------------------------------------------------------
// Segment sums: counts[k] += 1, dw[k][:] += flat[n][:], plus idx-as-float out.
__global__ __launch_bounds__(256) void scatter_kernel(const float* __restrict__ z_e,
                                                      const int* __restrict__ idx,
                                                      float* __restrict__ counts,
                                                      float* __restrict__ dw,
                                                      float* __restrict__ out_idxf) {
    const int n = blockIdx.x * 256 + threadIdx.x;
    const int k = idx[n];
    out_idxf[n] = (float)k;
    atomicAdd(&counts[k], 1.0f);
    const int b = n >> 12, hw = n & 4095;
    const float* ze = z_e + (size_t)b * DD * HWS + hw;
    float* dwr = dw + (size_t)k * DD;
    for (int d = 0; d < DD; ++d)
        atomicAdd(&dwr[d], ze[(size_t)d * HWS]);   // z_e read coalesced across lanes
}

// ---------------------------------------------------------------------------
__global__ __launch_bounds__(256) void finalize_kernel(const float* __restrict__ ema_count,
                                                       const float* __restrict__ ema_weight,
                                                       const float* __restrict__ counts,
                                                       const float* __restrict__ dw,
                                                       float* __restrict__ out_cb,
                                                       float* __restrict__ out_cnt,
                                                       float* __restrict__ out_w) {
    const int t = blockIdx.x * 256 + threadIdx.x;
    if (t < KC * DD) {
        const int k = t >> 8;
        const float nc = ema_count[k] * DECAYF + ONEMD * counts[k];
        const float nw = ema_weight[t] * DECAYF + ONEMD * dw[t];
        out_w[t] = nw;
        out_cb[t] = nw / (nc + EPSF);
        if ((t & 255) == 0) out_cnt[k] = nc;
    }
}

// ---------------------------------------------------------------------------
extern "C" void kernel_launch(void* const* d_in, const int* in_sizes, int n_in,
                              void* d_out, int out_size, void* d_ws, size_t ws_size,
                              hipStream_t stream) {
    const float* z_e       = (const float*)d_in[0];
    const float* codebook  = (const float*)d_in[1];
    const float* ema_count = (const float*)d_in[2];
    const float* ema_weight= (const float*)d_in[3];
    float* out = (float*)d_out;
    char* ws = (char*)d_ws;

    int*   ws_idx    = (int*)(ws + WS_IDX);
    float* ws_cnorm  = (float*)(ws + WS_CNORM);
    float* ws_counts = (float*)(ws + WS_COUNTS);
    float* ws_dw     = (float*)(ws + WS_DW);
    float* ws_lossp  = (float*)(ws + WS_LOSSP);

    // zero the accumulation buffers every call (ws is not re-poisoned between replays)
    hipMemsetAsync(ws + WS_COUNTS, 0, (size_t)(KC * 4 + KC * DD * 4), stream);

    cnorm_kernel<<<(KC + 255) / 256, 256, 0, stream>>>(codebook, ws_cnorm);
    argmin_kernel<<<NPTS / PT, 256, 0, stream>>>(z_e, codebook, ws_cnorm, ws_idx);
    zq_loss_kernel<<<NPTS * DD / 256 / 256 * 256 /*=65536*/, 256, 0, stream>>>(
        z_e, codebook, ws_idx, out + OUT_ZQ, ws_lossp);
    loss_finalize_kernel<<<1, 256, 0, stream>>>(ws_lossp, out + OUT_LOSS);
    scatter_kernel<<<NPTS / 256, 256, 0, stream>>>(z_e, ws_idx, ws_counts, ws_dw,
                                                   out + OUT_IDX);
    finalize_kernel<<<(KC * DD) / 256, 256, 0, stream>>>(ema_count, ema_weight,
                                                         ws_counts, ws_dw,
                                                         out + OUT_CB, out + OUT_CNT,
                                                         out + OUT_W);
}

// Round 2
// 1330.412 us; speedup vs baseline: 2.7724x; 2.7724x over previous
//
#include <hip/hip_runtime.h>
#include <hip/hip_bf16.h>

// VQ-VAE EMA vector quantizer, MI355X.
// z_e (16,256,64,64) f32, codebook (2048,256) f32, ema_count (2048) f32,
// ema_weight (2048,256) f32.
// Outputs (flat f32): z_q_st | idx-as-float | loss | new_codebook | new_ema_count | new_ema_weight

#define KC 2048
#define DD 256
#define NB 16
#define HWS 4096
#define NPTS 65536
#define DECAYF 0.99f
#define ONEMD 0.01f
#define EPSF 1e-5f
#define NCH 4

// ---- workspace layout (bytes) ----
#define WS_IDX     0                         // int32 [65536]
#define WS_SORTED  (WS_IDX + NPTS*4)         // int32 [65536]
#define WS_CNTI    (WS_SORTED + NPTS*4)      // int32 [2048]  (zeroed per call)
#define WS_START   (WS_CNTI + KC*4)          // int32 [2048]
#define WS_CURSOR  (WS_START + KC*4)         // int32 [2048]
#define WS_CNORM   (WS_CURSOR + KC*4)        // f32 [2048]
#define WS_LOSSP   (WS_CNORM + KC*4)         // f32 [65536]
#define WS_PART    (WS_LOSSP + NPTS*4)       // f32 [2048*NCH*256]  (8 MB, fully written)
#define WS_FLATT   (WS_PART + KC*NCH*DD*4)   // f32 [65536*256]     (64 MB)
#define WS_NEED_PART ((size_t)WS_FLATT)
#define WS_NEED_FULL ((size_t)WS_FLATT + (size_t)NPTS*DD*4)

// ---- output offsets (floats) ----
#define OUT_ZQ   0
#define OUT_IDX  16777216
#define OUT_LOSS (OUT_IDX + NPTS)
#define OUT_CB   (OUT_LOSS + 1)
#define OUT_CNT  (OUT_CB + KC*DD)
#define OUT_W    (OUT_CNT + KC)

// ---------------------------------------------------------------------------
__global__ __launch_bounds__(256) void cnorm_kernel(const float* __restrict__ cb,
                                                    float* __restrict__ cnorm) {
    int k = blockIdx.x * 256 + threadIdx.x;
    if (k < KC) {
        const float4* row = reinterpret_cast<const float4*>(cb + (size_t)k * DD);
        float s = 0.f;
        #pragma unroll 8
        for (int i = 0; i < DD / 4; ++i) {
            float4 v = row[i];
            s += v.x * v.x + v.y * v.y + v.z * v.z + v.w * v.w;
        }
        cnorm[k] = s;
    }
}

// ---------------------------------------------------------------------------
// Distance + argmin (fp32 VALU). dist' = ||c||^2 - 2*x.c
#define PT 64
#define KT 64
#define DC 64

__global__ __launch_bounds__(256) void argmin_kernel(const float* __restrict__ z_e,
                                                     const float* __restrict__ cb,
                                                     const float* __restrict__ cnorm,
                                                     int* __restrict__ idx_out) {
    __shared__ float As[DC][PT + 4];
    __shared__ float Bs[DC][KT + 4];
    __shared__ float rv[PT][16];
    __shared__ int   ri[PT][16];

    const int tid = threadIdx.x;
    const int tx = tid & 15, ty = tid >> 4;
    const int n0 = blockIdx.x * PT;
    const int b = n0 >> 12;
    const int hw0 = n0 & 4095;
    const float* zb = z_e + (size_t)b * DD * HWS + hw0;

    float bestv[4];
    int   besti[4];
    #pragma unroll
    for (int j = 0; j < 4; ++j) { bestv[j] = 3.4e38f; besti[j] = 0; }

    for (int kt = 0; kt < KC; kt += KT) {
        float acc[4][4] = {};
        for (int dc = 0; dc < DD; dc += DC) {
            #pragma unroll
            for (int i = 0; i < 16; ++i) {
                int li = tid + i * 256;
                int d = li >> 6, p = li & 63;
                As[d][p] = zb[(size_t)(dc + d) * HWS + p];
            }
            #pragma unroll
            for (int i = 0; i < 16; ++i) {
                int li = tid + i * 256;
                int k = li >> 6, d = li & 63;
                Bs[d][k] = cb[(size_t)(kt + k) * DD + dc + d];
            }
            __syncthreads();
            #pragma unroll
            for (int d = 0; d < DC; ++d) {
                const float4 a4 = *reinterpret_cast<const float4*>(&As[d][ty * 4]);
                const float4 b4 = *reinterpret_cast<const float4*>(&Bs[d][tx * 4]);
                const float a[4] = {a4.x, a4.y, a4.z, a4.w};
                const float bb[4] = {b4.x, b4.y, b4.z, b4.w};
                #pragma unroll
                for (int j = 0; j < 4; ++j)
                    #pragma unroll
                    for (int i = 0; i < 4; ++i)
                        acc[j][i] = fmaf(a[j], bb[i], acc[j][i]);
            }
            __syncthreads();
        }
        #pragma unroll
        for (int i = 0; i < 4; ++i) {
            int k = kt + tx * 4 + i;
            float c = cnorm[k];
            #pragma unroll
            for (int j = 0; j < 4; ++j) {
                float dist = c - 2.0f * acc[j][i];
                if (dist < bestv[j]) { bestv[j] = dist; besti[j] = k; }
            }
        }
    }

    #pragma unroll
    for (int j = 0; j < 4; ++j) {
        rv[ty * 4 + j][tx] = bestv[j];
        ri[ty * 4 + j][tx] = besti[j];
    }
    __syncthreads();
    if (tid < PT) {
        float bv = rv[tid][0];
        int bi = ri[tid][0];
        #pragma unroll
        for (int t = 1; t < 16; ++t) {
            float v = rv[tid][t];
            int i2 = ri[tid][t];
            if (v < bv || (v == bv && i2 < bi)) { bv = v; bi = i2; }
        }
        idx_out[n0 + tid] = bi;
    }
}

// ---------------------------------------------------------------------------
// Transpose z_e [B][D][HW] -> flatT [B*HW][D].  64x64 tiles via LDS.
__global__ __launch_bounds__(256) void transpose_kernel(const float* __restrict__ z_e,
                                                        float* __restrict__ flatT) {
    __shared__ float t_lds[64][65];
    const int tid = threadIdx.x;
    const int hw0 = blockIdx.x * 64;        // 64 tiles
    const int d0 = blockIdx.y * 64;         // 4 tiles
    const int b = blockIdx.z;               // 16
    const float* src = z_e + (size_t)b * DD * HWS;
    #pragma unroll
    for (int i = 0; i < 16; ++i) {
        int li = tid + i * 256;
        int d = li >> 6, hw = li & 63;
        t_lds[d][hw] = src[(size_t)(d0 + d) * HWS + hw0 + hw];
    }
    __syncthreads();
    float* dst = flatT + ((size_t)b * HWS + hw0) * DD + d0;
    #pragma unroll
    for (int i = 0; i < 16; ++i) {
        int li = tid + i * 256;
        int p = li >> 6, d = li & 63;
        dst[(size_t)p * DD + d] = t_lds[d][p];
    }
}

// ---------------------------------------------------------------------------
// Counting sort: histogram -> exclusive scan -> id scatter.
__global__ __launch_bounds__(256) void hist_kernel(const int* __restrict__ idx,
                                                   int* __restrict__ cnti) {
    int n = blockIdx.x * 256 + threadIdx.x;
    atomicAdd(&cnti[idx[n]], 1);
}

__global__ __launch_bounds__(256) void scan_kernel(const int* __restrict__ cnt,
                                                   int* __restrict__ start,
                                                   int* __restrict__ cursor) {
    __shared__ int ps[256];
    const int t = threadIdx.x;
    int v[8], s = 0;
    #pragma unroll
    for (int j = 0; j < 8; ++j) { v[j] = cnt[t * 8 + j]; s += v[j]; }
    ps[t] = s;
    __syncthreads();
    for (int off = 1; off < 256; off <<= 1) {
        int x = (t >= off) ? ps[t - off] : 0;
        __syncthreads();
        ps[t] += x;
        __syncthreads();
    }
    int base = ps[t] - s;   // exclusive prefix
    #pragma unroll
    for (int j = 0; j < 8; ++j) {
        start[t * 8 + j] = base;
        cursor[t * 8 + j] = base;
        base += v[j];
    }
}

__global__ __launch_bounds__(256) void scatter_ids_kernel(const int* __restrict__ idx,
                                                          int* __restrict__ cursor,
                                                          int* __restrict__ sorted,
                                                          float* __restrict__ out_idxf) {
    int n = blockIdx.x * 256 + threadIdx.x;
    int k = idx[n];
    out_idxf[n] = (float)k;
    int pos = atomicAdd(&cursor[k], 1);
    sorted[pos] = n;
}

// ---------------------------------------------------------------------------
// Segment sum dw: one block per (code k, chunk c); thread t owns dim t.
__global__ __launch_bounds__(256) void dw_flat_kernel(const float* __restrict__ flatT,
                                                      const int* __restrict__ sorted,
                                                      const int* __restrict__ start,
                                                      const int* __restrict__ cnti,
                                                      float* __restrict__ part) {
    const int k = blockIdx.x, c = blockIdx.y, t = threadIdx.x;
    const int s0 = start[k], cnt = cnti[k];
    float acc = 0.f;
    int p = c;
    for (; p + 3 * NCH < cnt; p += 4 * NCH) {
        int n0 = sorted[s0 + p];
        int n1 = sorted[s0 + p + NCH];
        int n2 = sorted[s0 + p + 2 * NCH];
        int n3 = sorted[s0 + p + 3 * NCH];
        acc += flatT[(size_t)n0 * DD + t];
        acc += flatT[(size_t)n1 * DD + t];
        acc += flatT[(size_t)n2 * DD + t];
        acc += flatT[(size_t)n3 * DD + t];
    }
    for (; p < cnt; p += NCH)
        acc += flatT[(size_t)sorted[s0 + p] * DD + t];
    part[((size_t)k * NCH + c) * DD + t] = acc;
}

// Fallback when ws can't hold flatT: same reduction, strided z_e reads.
__global__ __launch_bounds__(256) void dw_direct_kernel(const float* __restrict__ z_e,
                                                        const int* __restrict__ sorted,
                                                        const int* __restrict__ start,
                                                        const int* __restrict__ cnti,
                                                        float* __restrict__ part) {
    const int k = blockIdx.x, c = blockIdx.y, t = threadIdx.x;
    const int s0 = start[k], cnt = cnti[k];
    float acc = 0.f;
    for (int p = c; p < cnt; p += NCH) {
        int n = sorted[s0 + p];
        int b = n >> 12, hw = n & 4095;
        acc += z_e[(size_t)b * DD * HWS + (size_t)t * HWS + hw];
    }
    part[((size_t)k * NCH + c) * DD + t] = acc;
}

// ---------------------------------------------------------------------------
__global__ __launch_bounds__(256) void zq_loss_kernel(const float* __restrict__ z_e,
                                                      const float* __restrict__ cb,
                                                      const int* __restrict__ idx,
                                                      float* __restrict__ out_zq,
                                                      float* __restrict__ lossp) {
    const int tid = threadIdx.x;
    const size_t o = (size_t)blockIdx.x * 256 + tid;
    const int hw = (int)(o & 4095);
    const int d = (int)((o >> 12) & 255);
    const int b = (int)(o >> 20);
    const int n = b * HWS + hw;

    const float ze = z_e[o];
    const float q = cb[(size_t)idx[n] * DD + d];
    out_zq[o] = ze + (q - ze);
    float diff = ze - q;
    float v = diff * diff;

    #pragma unroll
    for (int off = 32; off > 0; off >>= 1) v += __shfl_down(v, off, 64);
    __shared__ float wsum[4];
    if ((tid & 63) == 0) wsum[tid >> 6] = v;
    __syncthreads();
    if (tid == 0) lossp[blockIdx.x] = wsum[0] + wsum[1] + wsum[2] + wsum[3];
}

__global__ __launch_bounds__(256) void loss_finalize_kernel(const float* __restrict__ lossp,
                                                            float* __restrict__ out_loss) {
    __shared__ double sd[256];
    const int tid = threadIdx.x;
    double s = 0.0;
    for (int i = tid; i < NPTS; i += 256) s += (double)lossp[i];
    sd[tid] = s;
    __syncthreads();
    for (int off = 128; off > 0; off >>= 1) {
        if (tid < off) sd[tid] += sd[tid + off];
        __syncthreads();
    }
    if (tid == 0) out_loss[0] = (float)(sd[0] / 16777216.0);
}

// ---------------------------------------------------------------------------
__global__ __launch_bounds__(256) void finalize_part_kernel(const float* __restrict__ ema_count,
                                                            const float* __restrict__ ema_weight,
                                                            const int* __restrict__ cnti,
                                                            const float* __restrict__ part,
                                                            float* __restrict__ out_cb,
                                                            float* __restrict__ out_cnt,
                                                            float* __restrict__ out_w) {
    const int t = blockIdx.x * 256 + threadIdx.x;
    const int k = t >> 8, d = t & 255;
    float dw = 0.f;
    #pragma unroll
    for (int c = 0; c < NCH; ++c) dw += part[((size_t)k * NCH + c) * DD + d];
    const float nc = ema_count[k] * DECAYF + ONEMD * (float)cnti[k];
    const float nw = ema_weight[t] * DECAYF + ONEMD * dw;
    out_w[t] = nw;
    out_cb[t] = nw / (nc + EPSF);
    if (d == 0) out_cnt[k] = nc;
}

// ---- legacy atomic fallback (only if ws is tiny) --------------------------
__global__ __launch_bounds__(256) void scatter_atomic_kernel(const float* __restrict__ z_e,
                                                             const int* __restrict__ idx,
                                                             float* __restrict__ counts,
                                                             float* __restrict__ dw,
                                                             float* __restrict__ out_idxf) {
    const int n = blockIdx.x * 256 + threadIdx.x;
    const int k = idx[n];
    out_idxf[n] = (float)k;
    atomicAdd(&counts[k], 1.0f);
    const int b = n >> 12, hw = n & 4095;
    const float* ze = z_e + (size_t)b * DD * HWS + hw;
    float* dwr = dw + (size_t)k * DD;
    for (int d = 0; d < DD; ++d)
        atomicAdd(&dwr[d], ze[(size_t)d * HWS]);
}

__global__ __launch_bounds__(256) void finalize_atomic_kernel(const float* __restrict__ ema_count,
                                                              const float* __restrict__ ema_weight,
                                                              const float* __restrict__ counts,
                                                              const float* __restrict__ dw,
                                                              float* __restrict__ out_cb,
                                                              float* __restrict__ out_cnt,
                                                              float* __restrict__ out_w) {
    const int t = blockIdx.x * 256 + threadIdx.x;
    const int k = t >> 8;
    const float nc = ema_count[k] * DECAYF + ONEMD * counts[k];
    const float nw = ema_weight[t] * DECAYF + ONEMD * dw[t];
    out_w[t] = nw;
    out_cb[t] = nw / (nc + EPSF);
    if ((t & 255) == 0) out_cnt[k] = nc;
}

// ---------------------------------------------------------------------------
extern "C" void kernel_launch(void* const* d_in, const int* in_sizes, int n_in,
                              void* d_out, int out_size, void* d_ws, size_t ws_size,
                              hipStream_t stream) {
    const float* z_e       = (const float*)d_in[0];
    const float* codebook  = (const float*)d_in[1];
    const float* ema_count = (const float*)d_in[2];
    const float* ema_weight= (const float*)d_in[3];
    float* out = (float*)d_out;
    char* ws = (char*)d_ws;

    int*   ws_idx    = (int*)(ws + WS_IDX);
    int*   ws_sorted = (int*)(ws + WS_SORTED);
    int*   ws_cnti   = (int*)(ws + WS_CNTI);
    int*   ws_start  = (int*)(ws + WS_START);
    int*   ws_cursor = (int*)(ws + WS_CURSOR);
    float* ws_cnorm  = (float*)(ws + WS_CNORM);
    float* ws_lossp  = (float*)(ws + WS_LOSSP);
    float* ws_part   = (float*)(ws + WS_PART);
    float* ws_flatT  = (float*)(ws + WS_FLATT);

    cnorm_kernel<<<(KC + 255) / 256, 256, 0, stream>>>(codebook, ws_cnorm);
    argmin_kernel<<<NPTS / PT, 256, 0, stream>>>(z_e, codebook, ws_cnorm, ws_idx);
    zq_loss_kernel<<<NPTS * DD / 256, 256, 0, stream>>>(z_e, codebook, ws_idx,
                                                        out + OUT_ZQ, ws_lossp);
    loss_finalize_kernel<<<1, 256, 0, stream>>>(ws_lossp, out + OUT_LOSS);

    if (ws_size >= WS_NEED_PART) {
        // counting-sort segment reduction (deterministic traffic, no fp atomics)
        hipMemsetAsync(ws + WS_CNTI, 0, KC * 4, stream);
        hist_kernel<<<NPTS / 256, 256, 0, stream>>>(ws_idx, ws_cnti);
        scan_kernel<<<1, 256, 0, stream>>>(ws_cnti, ws_start, ws_cursor);
        scatter_ids_kernel<<<NPTS / 256, 256, 0, stream>>>(ws_idx, ws_cursor, ws_sorted,
                                                           out + OUT_IDX);
        if (ws_size >= WS_NEED_FULL) {
            transpose_kernel<<<dim3(HWS / 64, DD / 64, NB), 256, 0, stream>>>(z_e, ws_flatT);
            dw_flat_kernel<<<dim3(KC, NCH), 256, 0, stream>>>(ws_flatT, ws_sorted,
                                                              ws_start, ws_cnti, ws_part);
        } else {
            dw_direct_kernel<<<dim3(KC, NCH), 256, 0, stream>>>(z_e, ws_sorted,
                                                                ws_start, ws_cnti, ws_part);
        }
        finalize_part_kernel<<<(KC * DD) / 256, 256, 0, stream>>>(ema_count, ema_weight,
                                                                  ws_cnti, ws_part,
                                                                  out + OUT_CB, out + OUT_CNT,
                                                                  out + OUT_W);
    } else {
        // legacy atomic path (tiny ws)
        float* counts_f = (float*)(ws + WS_PART);
        float* dw_buf   = (float*)(ws + WS_PART + KC * 4);
        hipMemsetAsync(ws + WS_PART, 0, KC * 4 + (size_t)KC * DD * 4, stream);
        scatter_atomic_kernel<<<NPTS / 256, 256, 0, stream>>>(z_e, ws_idx, counts_f,
                                                              dw_buf, out + OUT_IDX);
        finalize_atomic_kernel<<<(KC * DD) / 256, 256, 0, stream>>>(ema_count, ema_weight,
                                                                    counts_f, dw_buf,
                                                                    out + OUT_CB, out + OUT_CNT,
                                                                    out + OUT_W);
    }
}